// Round 9
// baseline (1125.421 us; speedup 1.0000x reference)
//
#include <hip/hip_runtime.h>

#define B_ 8
#define N_ 16384
#define F_ 6
#define M_ 128
#define K_ 16
#define D_ 768

typedef unsigned short u16;
typedef unsigned int u32;

// ---------------- FPS: f32, numpy sequential op order, first-index ties ----------------
#define FPT 16
__global__ __launch_bounds__(1024) void fps_kernel(const float* __restrict__ coords,
                                                   float* __restrict__ cent){
#pragma clang fp contract(off)
  int b = blockIdx.x;
  int t = threadIdx.x;
  const float* cb = coords + (size_t)b * N_ * 5;
  float px[FPT], py[FPT], pz[FPT], pw[FPT], md[FPT];
#pragma unroll
  for (int j = 0; j < FPT; j++){
    int i = t + j * 1024;
    px[j] = cb[(size_t)i*5+1]; py[j] = cb[(size_t)i*5+2];
    pz[j] = cb[(size_t)i*5+3]; pw[j] = cb[(size_t)i*5+4];
    md[j] = 1e30f;
  }
  __shared__ float s_c[4];
  __shared__ float s_wv[16];
  __shared__ int s_wi[16];
  if (t == 0){
    s_c[0]=cb[1]; s_c[1]=cb[2]; s_c[2]=cb[3]; s_c[3]=cb[4];
    float* c0 = cent + (size_t)b * M_ * 4;
    c0[0]=cb[1]; c0[1]=cb[2]; c0[2]=cb[3]; c0[3]=cb[4];
  }
  __syncthreads();
  for (int step = 1; step < M_; step++){
    float cx=s_c[0], cy=s_c[1], cz=s_c[2], ct=s_c[3];
    float bv = -1.0f; int bi = 1 << 30;
#pragma unroll
    for (int j = 0; j < FPT; j++){
      float dx=px[j]-cx, dy=py[j]-cy, dz=pz[j]-cz, dw=pw[j]-ct;
      float d = ((dx*dx + dy*dy) + dz*dz) + dw*dw;   // sequential sum, contract OFF
      float m = md[j];
      m = (d < m) ? d : m;
      md[j] = m;
      if (m > bv){ bv = m; bi = t + j * 1024; }      // first-max kept (ascending idx)
    }
#pragma unroll
    for (int off = 32; off > 0; off >>= 1){
      float ov = __shfl_down(bv, off);
      int oi = __shfl_down(bi, off);
      if (ov > bv || (ov == bv && oi < bi)){ bv = ov; bi = oi; }
    }
    if ((t & 63) == 0){ s_wv[t >> 6] = bv; s_wi[t >> 6] = bi; }
    __syncthreads();
    if (t == 0){
      float fv = s_wv[0]; int fi = s_wi[0];
      for (int w2 = 1; w2 < 16; w2++){
        float wv = s_wv[w2]; int wi = s_wi[w2];
        if (wv > fv || (wv == fv && wi < fi)){ fv = wv; fi = wi; }
      }
      fi &= (N_ - 1);
      const float* p = cb + (size_t)fi * 5 + 1;
      s_c[0]=p[0]; s_c[1]=p[1]; s_c[2]=p[2]; s_c[3]=p[3];
      float* cr = cent + ((size_t)b * M_ + step) * 4;
      cr[0]=p[0]; cr[1]=p[1]; cr[2]=p[2]; cr[3]=p[3];
    }
    __syncthreads();
  }
}

// ---------------- stable rank by centroid time; relabel early; f32 outputs ----------------
__global__ __launch_bounds__(128) void rank_scatter(const float* __restrict__ cent_fps,
                                                    float* __restrict__ cent_sorted,
                                                    float* __restrict__ out,
                                                    size_t out_elems){
  int b = blockIdx.x, m = threadIdx.x;
  __shared__ float tt[M_];
  const float* row = cent_fps + ((size_t)b * M_ + m) * 4;
  float x=row[0], y=row[1], z=row[2], w=row[3];
  tt[m] = w;
  __syncthreads();
  int rank = 0;
  for (int j = 0; j < M_; j++){
    float tj = tt[j];
    if (tj < w || (tj == w && j < m)) rank++;       // stable argsort semantics
  }
  float* dst = cent_sorted + ((size_t)b * M_ + rank) * 4;
  dst[0]=x; dst[1]=y; dst[2]=z; dst[3]=w;
  size_t co = (size_t)B_ * M_ * D_ + ((size_t)b * M_ + rank) * 4;
  if (co + 3 < out_elems){
    out[co+0]=x; out[co+1]=y; out[co+2]=z; out[co+3]=w;
  }
  size_t mo = (size_t)B_ * M_ * D_ + (size_t)B_ * M_ * 4 + (size_t)b * M_ + m;
  if (mo < out_elems) out[mo] = 1.0f;              // mask = True -> 1.0f
}

// ---------------- kNN: f32, np op order, stable-min extraction ----------------
#define KNT 512
#define KPT 32
__global__ __launch_bounds__(512) void knn_kernel(const float* __restrict__ coords,
                                                  const float* __restrict__ cent,
                                                  int* __restrict__ knn){
#pragma clang fp contract(off)
  int cm = blockIdx.x;
  int b = cm >> 7;
  const float* cb = coords + (size_t)b * N_ * 5;
  int t = threadIdx.x;
  float cx=cent[cm*4+0], cy=cent[cm*4+1], cz=cent[cm*4+2], ct=cent[cm*4+3];
  float dist[KPT];
#pragma unroll
  for (int j = 0; j < KPT; j++){
    size_t i = t + j * KNT;
    float dx=cb[i*5+1]-cx, dy=cb[i*5+2]-cy, dz=cb[i*5+3]-cz, dw=cb[i*5+4]-ct;
    float d = ((dx*dx + dy*dy) + dz*dz) + dw*dw;
    dist[j] = sqrtf(d);                            // IEEE f32 sqrt = np.sqrt(f32)
  }
  __shared__ float s_wv[8];
  __shared__ int s_wi[8];
  __shared__ int s_bi;
  for (int r = 0; r < K_; r++){
    float bv = 3e38f; int bi = 1 << 30;
#pragma unroll
    for (int j = 0; j < KPT; j++){
      int i = t + j * KNT;
      float v = dist[j];
      if (v < bv){ bv = v; bi = i; }               // first-min kept
    }
#pragma unroll
    for (int off = 32; off > 0; off >>= 1){
      float ov = __shfl_down(bv, off);
      int oi = __shfl_down(bi, off);
      if (ov < bv || (ov == bv && oi < bi)){ bv = ov; bi = oi; }
    }
    if ((t & 63) == 0){ s_wv[t >> 6] = bv; s_wi[t >> 6] = bi; }
    __syncthreads();
    if (t == 0){
      float fv = s_wv[0]; int fi = s_wi[0];
      for (int w = 1; w < 8; w++){
        float wv = s_wv[w]; int wi = s_wi[w];
        if (wv < fv || (wv == fv && wi < fi)){ fv = wv; fi = wi; }
      }
      s_bi = fi;
      knn[(size_t)cm * K_ + r] = fi & (N_ - 1);
    }
    __syncthreads();
    int wi = s_bi;
#pragma unroll
    for (int j = 0; j < KPT; j++){
      if (t + j * KNT == wi) dist[j] = 3e38f;
    }
  }
}

// ---------------- gather + layer0 (6->256, relu), all f32 ----------------
__global__ __launch_bounds__(256) void gather_l0(const float* __restrict__ feat,
                                                 const int* __restrict__ knn,
                                                 const float* __restrict__ W0,
                                                 const float* __restrict__ b0,
                                                 float* __restrict__ h1,
                                                 int rowBase){
  int lrow = blockIdx.x;
  int grow = rowBase + lrow;
  int b = grow >> 11;            // /(M*K)=2048
  int t = threadIdx.x;
  __shared__ float sf[F_];
  if (t < F_){
    int idx = knn[grow] & (N_ - 1);
    sf[t] = feat[((size_t)b * N_ + idx) * F_ + t];
  }
  __syncthreads();
  float acc = b0[t];
#pragma unroll
  for (int k = 0; k < F_; k++) acc = fmaf(sf[k], W0[k * 256 + t], acc);
  h1[(size_t)lrow * 256 + t] = fmaxf(acc, 0.0f);
}

// ---------------- plain f32 VALU GEMM: C = act(A[M,K] @ W[K,N] + bias) ----------------
template<int RELU>
__global__ __launch_bounds__(256) void gemm_f32(const float* __restrict__ A,
                                                const float* __restrict__ W,
                                                const float* __restrict__ bias,
                                                float* __restrict__ C,
                                                int Kd, int Nd){
  __shared__ float As[16][68];   // [k][m]
  __shared__ float Ws[16][68];   // [k][n]
  const int t = threadIdx.x;
  const int bm = blockIdx.y << 6;
  const int bn = blockIdx.x << 6;
  const int tx = t & 15, ty = t >> 4;
  float acc[4][4] = {};
  for (int k0 = 0; k0 < Kd; k0 += 16){
    {
      int r = t >> 2, c = (t & 3) << 2;
      const float4 a4 = *(const float4*)(A + (size_t)(bm + r) * Kd + k0 + c);
      As[c+0][r] = a4.x; As[c+1][r] = a4.y; As[c+2][r] = a4.z; As[c+3][r] = a4.w;
      int kk = t >> 4, cc = (t & 15) << 2;
      *(float4*)&Ws[kk][cc] = *(const float4*)(W + (size_t)(k0 + kk) * Nd + bn + cc);
    }
    __syncthreads();
#pragma unroll
    for (int k = 0; k < 16; k++){
      float4 av = *(const float4*)&As[k][ty << 2];
      float4 wv = *(const float4*)&Ws[k][tx << 2];
      float a[4] = {av.x, av.y, av.z, av.w};
      float w[4] = {wv.x, wv.y, wv.z, wv.w};
#pragma unroll
      for (int i = 0; i < 4; i++)
#pragma unroll
        for (int j = 0; j < 4; j++)
          acc[i][j] = fmaf(a[i], w[j], acc[i][j]);
    }
    __syncthreads();
  }
#pragma unroll
  for (int i = 0; i < 4; i++){
    int m = bm + (ty << 2) + i;
#pragma unroll
    for (int j = 0; j < 4; j++){
      int n = bn + (tx << 2) + j;
      float v = acc[i][j] + bias[n];
      if (RELU) v = fmaxf(v, 0.0f);
      C[(size_t)m * Nd + n] = v;
    }
  }
}

// ---------------- max-pool over 16-row groups (f32) ----------------
__global__ __launch_bounds__(256) void pool_kernel(const float* __restrict__ pf,
                                                   float* __restrict__ pooled,
                                                   int groupBase){
  int g = blockIdx.x;
  for (int d = threadIdx.x; d < D_; d += 256){
    float mx = -3e38f;
#pragma unroll
    for (int r = 0; r < K_; r++)
      mx = fmaxf(mx, pf[((size_t)g * K_ + r) * D_ + d]);
    pooled[(size_t)(groupBase + g) * D_ + d] = mx;
  }
}

// ---------------- tier fallback (f32) ----------------
__global__ __launch_bounds__(256) void fill_diag(float* __restrict__ out, size_t out_elems){
  size_t i = (size_t)blockIdx.x * 256 + threadIdx.x;
  if (i >= out_elems) return;
  size_t maskStart = (size_t)B_ * M_ * D_ + (size_t)B_ * M_ * 4;
  out[i] = (i >= maskStart) ? 1.0f : 0.0f;
}

extern "C" void kernel_launch(void* const* d_in, const int* in_sizes, int n_in,
                              void* d_out, int out_size, void* d_ws, size_t ws_size,
                              hipStream_t stream){
  (void)in_sizes; (void)n_in;
  const float* coords   = (const float*)d_in[0];
  const float* features = (const float*)d_in[1];
  const float* W0 = (const float*)d_in[2];  const float* b0 = (const float*)d_in[3];
  const float* W1 = (const float*)d_in[4];  const float* b1 = (const float*)d_in[5];
  const float* W2 = (const float*)d_in[6];  const float* b2 = (const float*)d_in[7];
  const float* W3 = (const float*)d_in[8];  const float* b3 = (const float*)d_in[9];
  const float* Wn0 = (const float*)d_in[10]; const float* bn0 = (const float*)d_in[11];
  const float* Wn1 = (const float*)d_in[12]; const float* bn1 = (const float*)d_in[13];
  float* out = (float*)d_out;
  const size_t out_elems = (size_t)out_size;

  char* ws = (char*)d_ws;
  const size_t o_centF = 0;            // 16 KB
  const size_t o_centS = 16384;        // 16 KB
  const size_t o_knn   = 32768;        // 64 KB
  const size_t o_pool  = 131072;       // 3,145,728 (f32 [1024,768])
  const size_t o_t1    = 3276800;      // 3,145,728
  const size_t o_chunk = 6422528;      // regA (R*3072 B) + regB (R*3072 B)
  const int ROWS = B_ * M_ * K_;       // 16384

  int R = 16384;
  while (R > 128 && o_chunk + (size_t)R * 6144 > ws_size) R >>= 1;
  if (d_ws == nullptr || o_chunk + (size_t)R * 6144 > ws_size){
    fill_diag<<<(int)((out_elems + 255) / 256), 256, 0, stream>>>(out, out_elems);
    return;
  }

  float* cent_fps    = (float*)(ws + o_centF);
  float* cent_sorted = (float*)(ws + o_centS);
  int*   knn         = (int*)(ws + o_knn);
  float* pooled = (float*)(ws + o_pool);
  float* t1     = (float*)(ws + o_t1);
  float* regA   = (float*)(ws + o_chunk);                      // h1 [R,256] then h3 [R,768]
  float* regB   = (float*)(ws + o_chunk + (size_t)R * 3072);   // h2 [R,512] then pf [R,768]

  fps_kernel<<<B_, 1024, 0, stream>>>(coords, cent_fps);
  rank_scatter<<<B_, 128, 0, stream>>>(cent_fps, cent_sorted, out, out_elems);
  knn_kernel<<<B_ * M_, KNT, 0, stream>>>(coords, cent_sorted, knn);

  for (int rowBase = 0; rowBase < ROWS; rowBase += R){
    gather_l0<<<R, 256, 0, stream>>>(features, knn, W0, b0, regA, rowBase);
    gemm_f32<1><<<dim3(512/64, R/64), 256, 0, stream>>>(regA, W1, b1, regB, 256, 512);
    gemm_f32<1><<<dim3(768/64, R/64), 256, 0, stream>>>(regB, W2, b2, regA, 512, 768);
    gemm_f32<0><<<dim3(768/64, R/64), 256, 0, stream>>>(regA, W3, b3, regB, 768, 768);
    pool_kernel<<<R / 16, 256, 0, stream>>>(regB, pooled, rowBase >> 4);
  }

  gemm_f32<1><<<dim3(768/64, (B_*M_)/64), 256, 0, stream>>>(pooled, Wn0, bn0, t1, 768, 768);
  gemm_f32<0><<<dim3(768/64, (B_*M_)/64), 256, 0, stream>>>(t1, Wn1, bn1, out, 768, 768);
}